// Round 1
// baseline (34.830 us; speedup 1.0000x reference)
//
#include <hip/hip_runtime.h>

// out[i] = in[i,0]*w + in[i,1]*(1-w), input [N,2] f32 row-major, output [N] f32.
// Pure streaming: 12 B traffic per row. Each thread handles 4 rows:
// reads 2x float4 (32 B), writes 1x float4 (16 B) -> fully coalesced 16B/lane.

__global__ void skip_kernel(const float4* __restrict__ in,
                            const float* __restrict__ weight,
                            float4* __restrict__ out,
                            int n4) {  // n4 = N/4 groups of 4 rows
    const float w  = weight[0];
    const float wm = 1.0f - w;
    const int stride = gridDim.x * blockDim.x;
    for (int i = blockIdx.x * blockDim.x + threadIdx.x; i < n4; i += stride) {
        // rows 4i..4i+3 live in two consecutive float4s:
        // a = (x0, y0, x1, y1), b = (x2, y2, x3, y3)
        const float4 a = in[2 * i];
        const float4 b = in[2 * i + 1];
        float4 o;
        o.x = fmaf(a.x, w, a.y * wm);
        o.y = fmaf(a.z, w, a.w * wm);
        o.z = fmaf(b.x, w, b.y * wm);
        o.w = fmaf(b.z, w, b.w * wm);
        out[i] = o;
    }
}

// Scalar tail safety net (N not divisible by 4) — not expected to fire for N=16M.
__global__ void skip_tail(const float* __restrict__ in,
                          const float* __restrict__ weight,
                          float* __restrict__ out,
                          int start, int n) {
    const float w  = weight[0];
    const float wm = 1.0f - w;
    int i = start + blockIdx.x * blockDim.x + threadIdx.x;
    if (i < n) {
        out[i] = fmaf(in[2 * i], w, in[2 * i + 1] * wm);
    }
}

extern "C" void kernel_launch(void* const* d_in, const int* in_sizes, int n_in,
                              void* d_out, int out_size, void* d_ws, size_t ws_size,
                              hipStream_t stream) {
    const float* in     = (const float*)d_in[0];
    const float* weight = (const float*)d_in[1];
    float* out          = (float*)d_out;

    const int n  = in_sizes[0] / 2;   // rows
    const int n4 = n / 4;

    const int block = 256;
    // Memory-bound: cap grid at 256 CUs x 8 blocks, grid-stride the rest (G11).
    int grid = (n4 + block - 1) / block;
    if (grid > 2048) grid = 2048;
    if (grid > 0) {
        skip_kernel<<<grid, block, 0, stream>>>(
            (const float4*)in, weight, (float4*)out, n4);
    }

    const int rem_start = n4 * 4;
    if (rem_start < n) {
        const int rem = n - rem_start;
        skip_tail<<<(rem + block - 1) / block, block, 0, stream>>>(
            in, weight, out, rem_start, rem);
    }
}

// Round 2
// 34.111 us; speedup vs baseline: 1.0211x; 1.0211x over previous
//
#include <hip/hip_runtime.h>

// out[i] = in[i,0]*w + in[i,1]*(1-w), input [N,2] f32 row-major, output [N] f32.
// Streaming, memory-bound. Layout trick: one float4 of input = 2 rows ->
// one float2 of output at the SAME flat index. So lane-contiguous float4
// loads pair with lane-contiguous float2 stores; every memory instruction
// has lanes at stride sizeof(access) (perfect coalescing).
// Each thread handles 2 float4s (32 B read, 16 B written), exact grid, no loop.

typedef float f4 __attribute__((ext_vector_type(4)));
typedef float f2 __attribute__((ext_vector_type(2)));

__global__ __launch_bounds__(256) void skip_kernel(const f4* __restrict__ in,
                                                   const float* __restrict__ weight,
                                                   f2* __restrict__ out,
                                                   int n4) {  // n4 = number of input float4s = N/2
    const float w  = weight[0];
    const float wm = 1.0f - w;
    const int base = blockIdx.x * (blockDim.x * 2) + threadIdx.x;

    // slot 0: lanes contiguous at `base`
    if (base < n4) {
        f4 a = __builtin_nontemporal_load(&in[base]);
        f2 o;
        o.x = fmaf(a.x, w, a.y * wm);
        o.y = fmaf(a.z, w, a.w * wm);
        __builtin_nontemporal_store(o, &out[base]);
    }
    // slot 1: lanes contiguous at `base + blockDim`
    const int base2 = base + blockDim.x;
    if (base2 < n4) {
        f4 b = __builtin_nontemporal_load(&in[base2]);
        f2 o;
        o.x = fmaf(b.x, w, b.y * wm);
        o.y = fmaf(b.z, w, b.w * wm);
        __builtin_nontemporal_store(o, &out[base2]);
    }
}

// Scalar tail for odd N (N=16M is even; safety net only).
__global__ void skip_tail(const float* __restrict__ in,
                          const float* __restrict__ weight,
                          float* __restrict__ out,
                          int start, int n) {
    const float w  = weight[0];
    const float wm = 1.0f - w;
    int i = start + blockIdx.x * blockDim.x + threadIdx.x;
    if (i < n) {
        out[i] = fmaf(in[2 * i], w, in[2 * i + 1] * wm);
    }
}

extern "C" void kernel_launch(void* const* d_in, const int* in_sizes, int n_in,
                              void* d_out, int out_size, void* d_ws, size_t ws_size,
                              hipStream_t stream) {
    const float* in     = (const float*)d_in[0];
    const float* weight = (const float*)d_in[1];
    float* out          = (float*)d_out;

    const int n  = in_sizes[0] / 2;  // rows
    const int n4 = n / 2;            // input float4 count (covers 2 rows each)

    const int block = 256;
    const int per_block = block * 2;             // float4s consumed per block
    const int grid = (n4 + per_block - 1) / per_block;  // exact grid: 16384 for N=16M
    if (grid > 0) {
        skip_kernel<<<grid, block, 0, stream>>>(
            (const f4*)in, weight, (f2*)out, n4);
    }

    const int rem_start = n4 * 2;  // rows covered by vector kernel
    if (rem_start < n) {
        const int rem = n - rem_start;
        skip_tail<<<(rem + block - 1) / block, block, 0, stream>>>(
            in, weight, out, rem_start, rem);
    }
}